// Round 4
// baseline (907.391 us; speedup 1.0000x reference)
//
#include <hip/hip_runtime.h>

#define NN 160
#define MAT (NN*NN)            // 25600
#define BCN 1024               // B*C
#define BIG ((size_t)BCN * MAT)
#define PKSZ 12800             // uints per bc in PK layout: 20 k8-groups * 160 * 4
#define ALPHA 0.05f
#define BETA  0.95f

typedef unsigned int u32;
typedef __attribute__((ext_vector_type(8))) short short8;   // 8 bf16 = 4 VGPRs
typedef __attribute__((ext_vector_type(4))) float f32x4;

// pack two fp32 -> bf16 pair (RNE), lo in low 16, hi in high 16
static __device__ __forceinline__ u32 pk2(float lo, float hi) {
    u32 a = __float_as_uint(lo), b = __float_as_uint(hi);
    a += 0x7fffu + ((a >> 16) & 1u);
    b += 0x7fffu + ((b >> 16) & 1u);
    return (a >> 16) | (b & 0xffff0000u);
}

// ---------------------------------------------------------------------------
// prep_sums: sums[v] = 1/(rowsum_v(a)+1), sums[160+v] = 1/(colsum_v(a)+1)
// ---------------------------------------------------------------------------
__global__ __launch_bounds__(256) void prep_sums(const float* __restrict__ a,
                                                 float* __restrict__ sums)
{
    __shared__ float rbuf[256], cbuf[256];
    int b = blockIdx.x, t = threadIdx.x;
    float r = 0.f, c = 0.f;
    if (t < NN) { r = a[b*NN + t]; c = a[t*NN + b]; }
    rbuf[t] = r; cbuf[t] = c;
    __syncthreads();
    for (int s = 128; s > 0; s >>= 1) {
        if (t < s) { rbuf[t] += rbuf[t+s]; cbuf[t] += cbuf[t+s]; }
        __syncthreads();
    }
    if (t == 0) {
        sums[b]      = 1.f / (rbuf[0] + 1.f);
        sums[NN + b] = 1.f / (cbuf[0] + 1.f);
    }
}

// ---------------------------------------------------------------------------
// prep_norm: A1f[v][w] = (a[v][w]+d)*rs[v]   (rownorm(a+I))
//            A2f[v][w] = (a[w][v]+d)*cs[v]   (rownorm(a^T+I))
// ---------------------------------------------------------------------------
__global__ __launch_bounds__(256) void prep_norm(
    const float* __restrict__ a, const float* __restrict__ sums,
    float* __restrict__ A1f, float* __restrict__ A2f)
{
    int i = blockIdx.x * 256 + threadIdx.x;   // 25600 exact (100 blocks)
    int v = i / NN, w = i % NN;
    float d = (v == w) ? 1.f : 0.f;
    A1f[i] = (a[v*NN + w] + d) * sums[v];
    A2f[i] = (a[w*NN + v] + d) * sums[NN + v];
}

// ---------------------------------------------------------------------------
// prep_mm: Ab = alpha*I + alpha*beta*A + beta^2 * A@A   for A1f and A2f
// ---------------------------------------------------------------------------
__global__ __launch_bounds__(256) void prep_mm(
    const float* __restrict__ A1f, const float* __restrict__ A2f,
    float* __restrict__ Ab1f, float* __restrict__ Ab2f)
{
    int idx = blockIdx.x * 256 + threadIdx.x;   // 51200 exact (200 blocks)
    int mtx = idx / MAT;
    int i = idx % MAT;
    int v = i / NN, l = i % NN;
    const float* A = mtx ? A2f : A1f;
    float s = 0.f;
    for (int w = 0; w < NN; ++w) s = fmaf(A[v*NN + w], A[w*NN + l], s);
    float d = (v == l) ? ALPHA : 0.f;
    float o = d + ALPHA*BETA*A[i] + BETA*BETA*s;
    (mtx ? Ab2f : Ab1f)[i] = o;
}

// ---------------------------------------------------------------------------
// prep_pk: pack 3 shared A-operand matrices into PK layout.
// G1 = At1@x + At2@x = (At1+At2)@x and G2 = (Ab1+Ab2)@x, so sum BEFORE pack:
// mtx 0: At12 = beta*(A1+A2) + 2*alpha*I ; 1: Ah12 = Ab1+Ab2 ; 2: a
// pk[k8][v][j] = pack(M[v][8k8+2j], M[v][8k8+2j+1])
// ---------------------------------------------------------------------------
__global__ __launch_bounds__(256) void prep_pk(
    const float* __restrict__ a, const float* __restrict__ A1f,
    const float* __restrict__ A2f, const float* __restrict__ Ab1f,
    const float* __restrict__ Ab2f,
    u32* __restrict__ At12pk, u32* __restrict__ Ah12pk, u32* __restrict__ apk)
{
    int idx = blockIdx.x * 256 + threadIdx.x;
    if (idx >= 3 * 3200) return;
    int mtx = idx / 3200;
    int r = idx % 3200;
    int k8 = r / 160, v = r % 160;
    u32 o[4];
    #pragma unroll
    for (int j = 0; j < 4; ++j) {
        int w0 = k8*8 + 2*j;
        float f0, f1;
        if (mtx == 0) {
            f0 = BETA*(A1f[v*NN + w0]     + A2f[v*NN + w0])     + ((v == w0)   ? 2.f*ALPHA : 0.f);
            f1 = BETA*(A1f[v*NN + w0 + 1] + A2f[v*NN + w0 + 1]) + ((v == w0+1) ? 2.f*ALPHA : 0.f);
        } else if (mtx == 1) {
            f0 = Ab1f[v*NN + w0]     + Ab2f[v*NN + w0];
            f1 = Ab1f[v*NN + w0 + 1] + Ab2f[v*NN + w0 + 1];
        } else {
            f0 = a[v*NN + w0];
            f1 = a[v*NN + w0 + 1];
        }
        o[j] = pk2(f0, f1);
    }
    u32* dst = (mtx == 0) ? At12pk : (mtx == 1) ? Ah12pk : apk;
    *(uint4*)&dst[(k8*160 + v)*4] = make_uint4(o[0], o[1], o[2], o[3]);
}

// ---------------------------------------------------------------------------
// cvt_x_pk: x fp32 [bc][v][l] -> PK (contraction dim = v):
//   xpk[bc][k8][l][j] = pack(x[8k8+2j][l], x[8k8+2j+1][l])
// one thread per uint4 (one (bc,k8,l))
// ---------------------------------------------------------------------------
__global__ __launch_bounds__(256) void cvt_x_pk(const float* __restrict__ x,
                                                u32* __restrict__ xpk)
{
    int idx = blockIdx.x * 256 + threadIdx.x;   // 3,276,800 (12800 blocks)
    int l  = idx % NN;
    int k8 = (idx / NN) % 20;
    int bc = idx / 3200;
    const float* xb = x + (size_t)bc * MAT + (size_t)(k8*8) * NN + l;
    u32 o[4];
    #pragma unroll
    for (int j = 0; j < 4; ++j)
        o[j] = pk2(xb[(2*j)*NN], xb[(2*j+1)*NN]);
    *(uint4*)&xpk[(size_t)bc * PKSZ + (size_t)(k8*160 + l)*4] =
        make_uint4(o[0], o[1], o[2], o[3]);
}

// ---------------------------------------------------------------------------
// bgemm16: per-block one bc. C[v][l] = sum_w A(v,w) * Q(w,l), MFMA 16x16x32 bf16.
// A, Q in PK layout. astride=0 for shared A, PKSZ for per-bc A.
// Cf: fp32 output (nullable); cacc: C += result; Cpk: PK output of raw result.
// 4 waves, each an 80x80 quadrant (5x5 tiles of 16x16), K-chunks of 32.
// ---------------------------------------------------------------------------
__global__ __launch_bounds__(256, 2) void bgemm16(
    const u32* __restrict__ Apk, long astride,
    const u32* __restrict__ Qpk,
    float* __restrict__ Cf, int cacc,
    u32* __restrict__ Cpk)
{
    __shared__ u32 As[2560];   // 4 k8-groups x 160 rows x 4 uints = 10240 B
    __shared__ u32 Bs[2560];
    int bc = blockIdx.x;
    int t = threadIdx.x;
    int lane = t & 63, w = t >> 6;
    int q = lane >> 4, ll = lane & 15;
    int v0w = (w >> 1) * 80, l0w = (w & 1) * 80;
    const u32* Ab = Apk + (size_t)bc * (size_t)astride;
    const u32* Qb = Qpk + (size_t)bc * PKSZ;

    f32x4 acc[5][5];
    #pragma unroll
    for (int rt = 0; rt < 5; ++rt)
        #pragma unroll
        for (int ct = 0; ct < 5; ++ct)
            acc[rt][ct] = (f32x4){0.f, 0.f, 0.f, 0.f};

    for (int c = 0; c < 5; ++c) {       // 5 K-chunks of 32
        __syncthreads();
        for (int i = t; i < 640; i += 256) {
            *(uint4*)&As[i*4] = *(const uint4*)&Ab[(size_t)c*2560 + i*4];
            *(uint4*)&Bs[i*4] = *(const uint4*)&Qb[(size_t)c*2560 + i*4];
        }
        __syncthreads();
        short8 af[5], bf[5];
        #pragma unroll
        for (int rt = 0; rt < 5; ++rt)
            af[rt] = *(const short8*)&As[(q*160 + v0w + rt*16 + ll)*4];
        #pragma unroll
        for (int ct = 0; ct < 5; ++ct)
            bf[ct] = *(const short8*)&Bs[(q*160 + l0w + ct*16 + ll)*4];
        #pragma unroll
        for (int rt = 0; rt < 5; ++rt)
            #pragma unroll
            for (int ct = 0; ct < 5; ++ct)
                acc[rt][ct] = __builtin_amdgcn_mfma_f32_16x16x32_bf16(
                    af[rt], bf[ct], acc[rt][ct], 0, 0, 0);
    }

    // epilogue: C/D layout col=lane&15, row=(lane>>4)*4+reg  [m89-verified]
    float* Cb = Cf  ? Cf  + (size_t)bc * MAT  : (float*)0;
    u32*   Pb = Cpk ? Cpk + (size_t)bc * PKSZ : (u32*)0;
    #pragma unroll
    for (int rt = 0; rt < 5; ++rt) {
        int vb = v0w + rt*16 + q*4;       // first of 4 consecutive rows
        #pragma unroll
        for (int ct = 0; ct < 5; ++ct) {
            int l = l0w + ct*16 + ll;
            f32x4 o = acc[rt][ct];
            if (Pb) {                     // PK of raw GEMM result
                int k8 = vb >> 3, j = (vb >> 1) & 3;
                size_t pa = (size_t)(k8*160 + l)*4 + j;
                Pb[pa]     = pk2(o.x, o.y);
                Pb[pa + 1] = pk2(o.z, o.w);
            }
            if (Cb) {
                size_t base = (size_t)vb * NN + l;
                if (cacc) {
                    o.x += Cb[base];
                    o.y += Cb[base + NN];
                    o.z += Cb[base + 2*NN];
                    o.w += Cb[base + 3*NN];
                }
                Cb[base]        = o.x;
                Cb[base + NN]   = o.y;
                Cb[base + 2*NN] = o.z;
                Cb[base + 3*NN] = o.w;
            }
        }
    }
}

// ---------------------------------------------------------------------------
// chanmix v5: one v-row per thread, ALL 32 output channels, j-interleaved lanes.
//  History: r0 128 accs -> spill (VGPR 72, +100MB scratch).  r1 threadIdx-
//  derived channel split -> W lost scalarness (SGPR 96->32, 2.3x).  r2 64 accs,
//  W scalar, but allocator targeted 8 waves/EU -> spill (VGPR 48, WRITE 307MB).
//  r3 16-acc block-split + waves_per_eu(2,4): no spill, W scalar, BUT block
//  pairs land on different XCDs (round-robin dispatch) -> FETCH doubled
//  (inputs 314MB > 256MB L3), and j=v0&3 constant per block -> embed_pk wave
//  writes were 16B-valid-per-64B-line, partials never merged across XCDs
//  (WRITE 279 vs 157 ideal).
//  v5 fixes all four:
//   - all 32 channels per thread (inputs read ONCE -> FETCH ~155MB)
//   - waves_per_eu(2,4): VGPR budget 128-256 for ~90 live -> no spill
//   - W indices loop-constant -> scalar s_load (SGPR high)
//   - lane map (vbit=tid&1, j=(tid>>1)&3, lsub=tid>>3): embed addr l*4+j is
//     CONSECUTIVE across even lanes -> full 128B wave writes, no partial lines
//   - embed v-pair via __shfl_down(e,1) (pair inside wave by construction)
// ---------------------------------------------------------------------------
__global__ __launch_bounds__(256) __attribute__((amdgpu_waves_per_eu(2, 4)))
void chanmix(
    const float* __restrict__ x, const float* __restrict__ g1, const float* __restrict__ g2,
    const float* __restrict__ We, const float* __restrict__ be,
    const float* __restrict__ Wp, const float* __restrict__ bp,
    u32* __restrict__ embed_pk, float* __restrict__ pool)
{
    int tid  = threadIdx.x;
    int vbit = tid & 1;
    int jj   = (tid >> 1) & 3;          // PK j index: varies WITHIN the wave
    int lsub = tid >> 3;                // 0..31
    int bid  = blockIdx.x;              // 3200 = 32 b * 20 v0g * 5 lg
    int b    = bid / 100;
    int r    = bid % 100;
    int v0g  = r / 5;                   // k8 group, 0..19
    int lg   = r % 5;
    int v0   = 4*v0g + jj;              // 0..79
    int v    = 2*v0 + vbit;             // 0..159
    int l    = 32*lg + lsub;            // 0..159
    size_t base = (size_t)b * (32*MAT) + (size_t)v * NN + l;

    float e[32], p[32];
    #pragma unroll
    for (int o = 0; o < 32; ++o) {
        e[o] = 2.f * be[o];
        p[o] = 2.f * bp[o];
    }
    #pragma unroll 1
    for (int k = 0; k < 3; ++k) {
        const float* s = (k == 0) ? x : ((k == 1) ? g1 : g2);
        float sc = (k == 0) ? 2.f : 1.f;
        #pragma unroll 1
        for (int c4 = 0; c4 < 8; ++c4) {        // 32 channels in chunks of 4
            float h[4];
            #pragma unroll
            for (int j = 0; j < 4; ++j)
                h[j] = s[base + (size_t)(c4*4 + j)*MAT] * sc;
            #pragma unroll
            for (int o = 0; o < 32; ++o) {
                f32x4 we = *(const f32x4*)&We[o*96 + k*32 + c4*4];   // uniform -> SGPR
                f32x4 wp = *(const f32x4*)&Wp[o*96 + k*32 + c4*4];   // uniform -> SGPR
                #pragma unroll
                for (int j = 0; j < 4; ++j) {
                    e[o] = fmaf(we[j], h[j], e[o]);
                    p[o] = fmaf(wp[j], h[j], p[o]);
                }
            }
        }
    }
    // k8 = v0>>2 == v0g (block-uniform); embed uint index = k8*640 + l*4 + jj
    // -> consecutive across even lanes (jj fastest, then l): full-line writes.
    #pragma unroll
    for (int o = 0; o < 32; ++o) {
        size_t bo = (size_t)(b*32 + o);
        pool[bo*MAT + (size_t)v*NN + l] = p[o];
        float en = __shfl_down(e[o], 1);        // partner lane = v+1's e[o]
        if (vbit == 0)
            embed_pk[bo*PKSZ + (size_t)(v0g*160 + l)*4 + jj] = pk2(e[o], en);
    }
}

// ---------------------------------------------------------------------------
// softmax over node dim (read-only input); emits srpk = PK over node-row pairs
// (B-operand of a@s and A-operand of s^T@embed) AND scpk = PK over column
// pairs (A-operand of s@M, was the separate tpack kernel).  Column-pair values
// come from the neighbor lane via shfl (lane parity == l parity since 160 and
// 64 are even; pair never straddles a wave).  fp32 s is never stored.
// ---------------------------------------------------------------------------
__global__ __launch_bounds__(256) void softmax_n(const float* __restrict__ p,
                                                 u32* __restrict__ srpk,
                                                 u32* __restrict__ scpk)
{
    int idx = blockIdx.x * 256 + threadIdx.x;   // 163,840 columns
    int l  = idx % NN;
    int bo = idx / NN;
    const float* col = p + (size_t)bo * MAT + l;
    float m = -1e30f, s = 0.f;
    for (int n = 0; n < NN; ++n) {
        float v  = col[(size_t)n * NN];
        float mn = fmaxf(m, v);
        s = s * __expf(m - mn) + __expf(v - mn);
        m = mn;
    }
    float inv = 1.f / s;
    u32* sp = srpk + (size_t)bo * PKSZ;
    u32* cp = scpk + (size_t)bo * PKSZ;
    int k8c = l >> 3, jc = (l >> 1) & 3;
    bool wlane = ((l & 1) == 0);
    for (int k2 = 0; k2 < 80; ++k2) {
        float s0 = __expf(col[(size_t)(2*k2)   * NN] - m) * inv;
        float s1 = __expf(col[(size_t)(2*k2+1) * NN] - m) * inv;
        sp[(size_t)((k2 >> 2)*160 + l)*4 + (k2 & 3)] = pk2(s0, s1);
        float t0 = __shfl_down(s0, 1);
        float t1 = __shfl_down(s1, 1);
        if (wlane) {
            cp[(size_t)(k8c*160 + 2*k2)*4 + jc]     = pk2(s0, t0);
            cp[(size_t)(k8c*160 + 2*k2 + 1)*4 + jc] = pk2(s1, t1);
        }
    }
}

// ---------------------------------------------------------------------------
extern "C" void kernel_launch(void* const* d_in, const int* in_sizes, int n_in,
                              void* d_out, int out_size, void* d_ws, size_t ws_size,
                              hipStream_t stream)
{
    const float* x  = (const float*)d_in[0];
    const float* a  = (const float*)d_in[1];
    const float* We = (const float*)d_in[2];
    const float* be = (const float*)d_in[3];
    const float* Wp = (const float*)d_in[4];
    const float* bp = (const float*)d_in[5];

    float* part0 = (float*)d_out;          // pool -> x_new
    float* part1 = part0 + BIG;            // G2 -> a_new

    char* ws = (char*)d_ws;
    // persistent small PK mats: 3 x 51200 B
    u32* At12pk = (u32*)(ws + 0);
    u32* Ah12pk = (u32*)(ws + 51200);
    u32* apk    = (u32*)(ws + 102400);
    // big regions
    float* B1      = (float*)(ws + 256000);                 // 104,857,600 B: G1 -> srpk+scpk
    u32*   R3      = (u32*)  (ws + 256000 + 104857600);     //  52,428,800 B: x_pk -> embed_pk
    u32*   R4      = (u32*)  (ws + 256000 + 157286400);     //  52,428,800 B: M_pk
    // total: 209,971,200 B
    // prep-phase temps live inside B1 (dead before first bgemm writes B1)
    float* sums = B1;                       // 320 floats
    float* A1f  = (float*)((char*)B1 + 1536);
    float* A2f  = A1f + MAT;
    float* Ab1f = A2f + MAT;
    float* Ab2f = Ab1f + MAT;
    u32* x_pk     = R3;
    u32* embed_pk = R3;
    u32* srpk = (u32*)B1;
    u32* scpk = (u32*)((char*)B1 + 52428800);
    u32* M_pk = R4;

    // ---- prep (tiny) ----
    prep_sums<<<160, 256, 0, stream>>>(a, sums);
    prep_norm<<<100, 256, 0, stream>>>(a, sums, A1f, A2f);
    prep_mm  <<<200, 256, 0, stream>>>(A1f, A2f, Ab1f, Ab2f);
    prep_pk  <<<38, 256, 0, stream>>>(a, A1f, A2f, Ab1f, Ab2f,
                                      At12pk, Ah12pk, apk);
    cvt_x_pk <<<12800, 256, 0, stream>>>(x, x_pk);

    // ---- hop GEMMs (merged: G1 = (At1+At2)@x, G2 = (Ab1+Ab2)@x) ----
    bgemm16<<<BCN, 256, 0, stream>>>(At12pk, 0, x_pk, B1,    0, (u32*)0);  // G1
    bgemm16<<<BCN, 256, 0, stream>>>(Ah12pk, 0, x_pk, part1, 0, (u32*)0);  // G2

    // ---- channel mix + softmax(+packs fused) ----
    chanmix<<<3200, 256, 0, stream>>>(x, B1, part1, We, be, Wp, bp, embed_pk, part0);
    softmax_n<<<640, 256, 0, stream>>>(part0, srpk, scpk);

    // ---- output GEMMs ----
    // M = a@s (PK-only output)
    bgemm16<<<BCN, 256, 0, stream>>>(apk, 0, srpk, (float*)0, 0, M_pk);
    // x_new = s^T @ embed
    bgemm16<<<BCN, 256, 0, stream>>>(srpk, (long)PKSZ, embed_pk, part0, 0, (u32*)0);
    // a_new = s @ M
    bgemm16<<<BCN, 256, 0, stream>>>(scpk, (long)PKSZ, M_pk, part1, 0, (u32*)0);
}

// Round 5
// 673.137 us; speedup vs baseline: 1.3480x; 1.3480x over previous
//
#include <hip/hip_runtime.h>

#define NN 160
#define MAT (NN*NN)            // 25600
#define BCN 1024               // B*C
#define BIG ((size_t)BCN * MAT)
#define PKSZ 12800             // uints per bc in PK layout: 20 k8-groups * 160 * 4
#define ALPHA 0.05f
#define BETA  0.95f

typedef unsigned int u32;
typedef __attribute__((ext_vector_type(8))) short short8;   // 8 bf16 = 4 VGPRs
typedef __attribute__((ext_vector_type(4))) float f32x4;

// pack two fp32 -> bf16 pair (RNE), lo in low 16, hi in high 16
static __device__ __forceinline__ u32 pk2(float lo, float hi) {
    u32 a = __float_as_uint(lo), b = __float_as_uint(hi);
    a += 0x7fffu + ((a >> 16) & 1u);
    b += 0x7fffu + ((b >> 16) & 1u);
    return (a >> 16) | (b & 0xffff0000u);
}

// ---------------------------------------------------------------------------
// prep_sums: sums[v] = 1/(rowsum_v(a)+1), sums[160+v] = 1/(colsum_v(a)+1)
// ---------------------------------------------------------------------------
__global__ __launch_bounds__(256) void prep_sums(const float* __restrict__ a,
                                                 float* __restrict__ sums)
{
    __shared__ float rbuf[256], cbuf[256];
    int b = blockIdx.x, t = threadIdx.x;
    float r = 0.f, c = 0.f;
    if (t < NN) { r = a[b*NN + t]; c = a[t*NN + b]; }
    rbuf[t] = r; cbuf[t] = c;
    __syncthreads();
    for (int s = 128; s > 0; s >>= 1) {
        if (t < s) { rbuf[t] += rbuf[t+s]; cbuf[t] += cbuf[t+s]; }
        __syncthreads();
    }
    if (t == 0) {
        sums[b]      = 1.f / (rbuf[0] + 1.f);
        sums[NN + b] = 1.f / (cbuf[0] + 1.f);
    }
}

// ---------------------------------------------------------------------------
// prep_norm: A1f[v][w] = (a[v][w]+d)*rs[v]   (rownorm(a+I))
//            A2f[v][w] = (a[w][v]+d)*cs[v]   (rownorm(a^T+I))
// ---------------------------------------------------------------------------
__global__ __launch_bounds__(256) void prep_norm(
    const float* __restrict__ a, const float* __restrict__ sums,
    float* __restrict__ A1f, float* __restrict__ A2f)
{
    int i = blockIdx.x * 256 + threadIdx.x;   // 25600 exact (100 blocks)
    int v = i / NN, w = i % NN;
    float d = (v == w) ? 1.f : 0.f;
    A1f[i] = (a[v*NN + w] + d) * sums[v];
    A2f[i] = (a[w*NN + v] + d) * sums[NN + v];
}

// ---------------------------------------------------------------------------
// prep_mm: Ab = alpha*I + alpha*beta*A + beta^2 * A@A   for A1f and A2f
// ---------------------------------------------------------------------------
__global__ __launch_bounds__(256) void prep_mm(
    const float* __restrict__ A1f, const float* __restrict__ A2f,
    float* __restrict__ Ab1f, float* __restrict__ Ab2f)
{
    int idx = blockIdx.x * 256 + threadIdx.x;   // 51200 exact (200 blocks)
    int mtx = idx / MAT;
    int i = idx % MAT;
    int v = i / NN, l = i % NN;
    const float* A = mtx ? A2f : A1f;
    float s = 0.f;
    for (int w = 0; w < NN; ++w) s = fmaf(A[v*NN + w], A[w*NN + l], s);
    float d = (v == l) ? ALPHA : 0.f;
    float o = d + ALPHA*BETA*A[i] + BETA*BETA*s;
    (mtx ? Ab2f : Ab1f)[i] = o;
}

// ---------------------------------------------------------------------------
// prep_pk: pack 3 shared A-operand matrices into PK layout.
// G1 = At1@x + At2@x = (At1+At2)@x and G2 = (Ab1+Ab2)@x, so sum BEFORE pack:
// mtx 0: At12 = beta*(A1+A2) + 2*alpha*I ; 1: Ah12 = Ab1+Ab2 ; 2: a
// pk[k8][v][j] = pack(M[v][8k8+2j], M[v][8k8+2j+1])
// ---------------------------------------------------------------------------
__global__ __launch_bounds__(256) void prep_pk(
    const float* __restrict__ a, const float* __restrict__ A1f,
    const float* __restrict__ A2f, const float* __restrict__ Ab1f,
    const float* __restrict__ Ab2f,
    u32* __restrict__ At12pk, u32* __restrict__ Ah12pk, u32* __restrict__ apk)
{
    int idx = blockIdx.x * 256 + threadIdx.x;
    if (idx >= 3 * 3200) return;
    int mtx = idx / 3200;
    int r = idx % 3200;
    int k8 = r / 160, v = r % 160;
    u32 o[4];
    #pragma unroll
    for (int j = 0; j < 4; ++j) {
        int w0 = k8*8 + 2*j;
        float f0, f1;
        if (mtx == 0) {
            f0 = BETA*(A1f[v*NN + w0]     + A2f[v*NN + w0])     + ((v == w0)   ? 2.f*ALPHA : 0.f);
            f1 = BETA*(A1f[v*NN + w0 + 1] + A2f[v*NN + w0 + 1]) + ((v == w0+1) ? 2.f*ALPHA : 0.f);
        } else if (mtx == 1) {
            f0 = Ab1f[v*NN + w0]     + Ab2f[v*NN + w0];
            f1 = Ab1f[v*NN + w0 + 1] + Ab2f[v*NN + w0 + 1];
        } else {
            f0 = a[v*NN + w0];
            f1 = a[v*NN + w0 + 1];
        }
        o[j] = pk2(f0, f1);
    }
    u32* dst = (mtx == 0) ? At12pk : (mtx == 1) ? Ah12pk : apk;
    *(uint4*)&dst[(k8*160 + v)*4] = make_uint4(o[0], o[1], o[2], o[3]);
}

// ---------------------------------------------------------------------------
// prep_wpk: pack the stacked channel-mix weights into PK A-operand layout.
// Wfold rows 0..31 = We, 32..63 = Wp; columns 0..31 (the x block) scaled 2x
// (embed = We@[2x, G1, G2] + 2be after merging the a / a^T mixprops).
// Wpk[(k8c*64 + m)*4 + j] = pk2(Wfold[m][8k8c+2j], Wfold[m][8k8c+2j+1])
// ---------------------------------------------------------------------------
__global__ __launch_bounds__(256) void prep_wpk(
    const float* __restrict__ We, const float* __restrict__ Wp,
    u32* __restrict__ Wpk)
{
    int idx = blockIdx.x * 256 + threadIdx.x;   // 768 = 12 k8c * 64 m
    if (idx >= 768) return;
    int k8c = idx / 64, m = idx % 64;
    const float* W = (m < 32) ? We + m*96 : Wp + (m-32)*96;
    float sc = (k8c < 4) ? 2.f : 1.f;          // columns 0..31 are the x block
    u32 o[4];
    #pragma unroll
    for (int j = 0; j < 4; ++j) {
        int c0 = k8c*8 + 2*j;
        o[j] = pk2(W[c0]*sc, W[c0+1]*sc);
    }
    *(uint4*)&Wpk[idx*4] = make_uint4(o[0], o[1], o[2], o[3]);
}

// ---------------------------------------------------------------------------
// cvt_x_pk: x fp32 [bc][v][l] -> PK (contraction dim = v):
//   xpk[bc][k8][l][j] = pack(x[8k8+2j][l], x[8k8+2j+1][l])
// one thread per uint4 (one (bc,k8,l))
// ---------------------------------------------------------------------------
__global__ __launch_bounds__(256) void cvt_x_pk(const float* __restrict__ x,
                                                u32* __restrict__ xpk)
{
    int idx = blockIdx.x * 256 + threadIdx.x;   // 3,276,800 (12800 blocks)
    int l  = idx % NN;
    int k8 = (idx / NN) % 20;
    int bc = idx / 3200;
    const float* xb = x + (size_t)bc * MAT + (size_t)(k8*8) * NN + l;
    u32 o[4];
    #pragma unroll
    for (int j = 0; j < 4; ++j)
        o[j] = pk2(xb[(2*j)*NN], xb[(2*j+1)*NN]);
    *(uint4*)&xpk[(size_t)bc * PKSZ + (size_t)(k8*160 + l)*4] =
        make_uint4(o[0], o[1], o[2], o[3]);
}

// ---------------------------------------------------------------------------
// bgemm16: per-block one bc. C[v][l] = sum_w A(v,w) * Q(w,l), MFMA 16x16x32 bf16.
// A, Q in PK layout. astride=0 for shared A, PKSZ for per-bc A.
// Cf: fp32 output (nullable); cacc: C += result; Cpk: PK output of raw result.
// 4 waves, each an 80x80 quadrant (5x5 tiles of 16x16), K-chunks of 32.
// ---------------------------------------------------------------------------
__global__ __launch_bounds__(256, 2) void bgemm16(
    const u32* __restrict__ Apk, long astride,
    const u32* __restrict__ Qpk,
    float* __restrict__ Cf, int cacc,
    u32* __restrict__ Cpk)
{
    __shared__ u32 As[2560];   // 4 k8-groups x 160 rows x 4 uints = 10240 B
    __shared__ u32 Bs[2560];
    int bc = blockIdx.x;
    int t = threadIdx.x;
    int lane = t & 63, w = t >> 6;
    int q = lane >> 4, ll = lane & 15;
    int v0w = (w >> 1) * 80, l0w = (w & 1) * 80;
    const u32* Ab = Apk + (size_t)bc * (size_t)astride;
    const u32* Qb = Qpk + (size_t)bc * PKSZ;

    f32x4 acc[5][5];
    #pragma unroll
    for (int rt = 0; rt < 5; ++rt)
        #pragma unroll
        for (int ct = 0; ct < 5; ++ct)
            acc[rt][ct] = (f32x4){0.f, 0.f, 0.f, 0.f};

    for (int c = 0; c < 5; ++c) {       // 5 K-chunks of 32
        __syncthreads();
        for (int i = t; i < 640; i += 256) {
            *(uint4*)&As[i*4] = *(const uint4*)&Ab[(size_t)c*2560 + i*4];
            *(uint4*)&Bs[i*4] = *(const uint4*)&Qb[(size_t)c*2560 + i*4];
        }
        __syncthreads();
        short8 af[5], bf[5];
        #pragma unroll
        for (int rt = 0; rt < 5; ++rt)
            af[rt] = *(const short8*)&As[(q*160 + v0w + rt*16 + ll)*4];
        #pragma unroll
        for (int ct = 0; ct < 5; ++ct)
            bf[ct] = *(const short8*)&Bs[(q*160 + l0w + ct*16 + ll)*4];
        #pragma unroll
        for (int rt = 0; rt < 5; ++rt)
            #pragma unroll
            for (int ct = 0; ct < 5; ++ct)
                acc[rt][ct] = __builtin_amdgcn_mfma_f32_16x16x32_bf16(
                    af[rt], bf[ct], acc[rt][ct], 0, 0, 0);
    }

    // epilogue: C/D layout col=lane&15, row=(lane>>4)*4+reg  [m89-verified]
    float* Cb = Cf  ? Cf  + (size_t)bc * MAT  : (float*)0;
    u32*   Pb = Cpk ? Cpk + (size_t)bc * PKSZ : (u32*)0;
    #pragma unroll
    for (int rt = 0; rt < 5; ++rt) {
        int vb = v0w + rt*16 + q*4;       // first of 4 consecutive rows
        #pragma unroll
        for (int ct = 0; ct < 5; ++ct) {
            int l = l0w + ct*16 + ll;
            f32x4 o = acc[rt][ct];
            if (Pb) {                     // PK of raw GEMM result
                int k8 = vb >> 3, j = (vb >> 1) & 3;
                size_t pa = (size_t)(k8*160 + l)*4 + j;
                Pb[pa]     = pk2(o.x, o.y);
                Pb[pa + 1] = pk2(o.z, o.w);
            }
            if (Cb) {
                size_t base = (size_t)vb * NN + l;
                if (cacc) {
                    o.x += Cb[base];
                    o.y += Cb[base + NN];
                    o.z += Cb[base + 2*NN];
                    o.w += Cb[base + 3*NN];
                }
                Cb[base]        = o.x;
                Cb[base + NN]   = o.y;
                Cb[base + 2*NN] = o.z;
                Cb[base + 3*NN] = o.w;
            }
        }
    }
}

// ---------------------------------------------------------------------------
// chanmix_mm: the channel mix as an MFMA GEMM.
//   out[64, pos] = Wfold[64,96] @ h[96, pos],  h = stacked(x, G1, G2)
// History: 4 rounds of scalar-FMA chanmix all lost to the compiler's
// memory-bound perf-hint (targets 8 waves/EU, spills accumulators; r4: ideal
// HBM traffic 154+154MB but VGPR=52 -> L2-resident scratch churn, 414us,
// 761GB/s).  bgemm16 proves MFMA kernels keep 100+ VGPRs spill-free, so the
// accumulators move to MFMA tiles.
// Block = (b, k8v in 0..19, l-chunk of 32): 8 v-rows x 32 l = 256 positions.
//  - stage h fp32->bf16-PK in LDS: hs[12 k8c][256 p][4 j], p = vsub*32+lsub
//  - W PK in LDS (12KB), loaded from Wpk
//  - 4 waves x 16 M-rows; waves 0,1 = embed channels, 2,3 = pool channels
//  - per wave: 16 n-tiles x 3 K-chunks = 48 MFMA, acc[16] f32x4
//  - embed v-pair pk2 is register-local (acc[nt] pairs acc[nt+2]); each lane
//    stores full uint4 -> 256B contiguous per 16 lanes (full lines, keeps
//    r4's ideal WRITE_SIZE)
//  - pool: 16 lanes x 64B segments, lh 0/1 completes each 128B line in-wave
// ---------------------------------------------------------------------------
__global__ __launch_bounds__(256, 2) void chanmix_mm(
    const float* __restrict__ x, const float* __restrict__ g1,
    const float* __restrict__ g2, const u32* __restrict__ Wpk,
    const float* __restrict__ be, const float* __restrict__ bp,
    u32* __restrict__ embed_pk, float* __restrict__ pool)
{
    __shared__ u32 hs[12288];   // 48 KB: [12 k8c][256 p][4 j]
    __shared__ u32 wl[3072];    // 12 KB: [12 k8c][64 m][4 j]
    int t = threadIdx.x;
    int bid = blockIdx.x;       // 3200 = 32 b * 20 k8v * 5 lg
    int b   = bid / 100;
    int r   = bid % 100;
    int k8v = r / 5;
    int l0  = (r % 5) * 32;

    // W -> LDS (768 uint4)
    #pragma unroll
    for (int i = 0; i < 3; ++i) {
        int ii = i*256 + t;
        *(uint4*)&wl[ii*4] = *(const uint4*)&Wpk[ii*4];
    }

    // stage h: thread t handles position p = t (vsub = t>>5, lsub = t&31)
    {
        int vsub = t >> 5, lsub = t & 31;
        size_t poff  = (size_t)(k8v*8 + vsub) * NN + l0 + lsub;
        size_t bbase = (size_t)b * (size_t)(32*MAT);
        #pragma unroll 4
        for (int k8c = 0; k8c < 12; ++k8c) {
            u32 o4[4];
            #pragma unroll
            for (int j = 0; j < 4; ++j) {
                int c0 = k8c*8 + 2*j;   // c0 even; c0,c0+1 in same source
                const float* pl = (c0 < 32) ? x  + bbase + (size_t)c0*MAT
                                : (c0 < 64) ? g1 + bbase + (size_t)(c0-32)*MAT
                                            : g2 + bbase + (size_t)(c0-64)*MAT;
                o4[j] = pk2(pl[poff], pl[poff + MAT]);
            }
            *(uint4*)&hs[(k8c*256 + t)*4] = make_uint4(o4[0], o4[1], o4[2], o4[3]);
        }
    }
    __syncthreads();

    int lane = t & 63, w = t >> 6;
    int q = lane >> 4, ll = lane & 15;

    f32x4 acc[16];
    #pragma unroll
    for (int nt = 0; nt < 16; ++nt) acc[nt] = (f32x4){0.f, 0.f, 0.f, 0.f};

    #pragma unroll
    for (int kc = 0; kc < 3; ++kc) {
        short8 af = *(const short8*)&wl[((kc*4 + q)*64 + w*16 + ll)*4];
        #pragma unroll
        for (int nt = 0; nt < 16; ++nt) {
            short8 bf = *(const short8*)&hs[((kc*4 + q)*256 + nt*16 + ll)*4];
            acc[nt] = __builtin_amdgcn_mfma_f32_16x16x32_bf16(af, bf, acc[nt], 0, 0, 0);
        }
    }

    // epilogue: D row = q*4+reg within wave's 16-row tile, col = ll
    int m0 = w*16 + q*4;
    if (w >= 2) {
        // pool channels o = m0-32+reg
        #pragma unroll
        for (int nt = 0; nt < 16; ++nt) {
            int v = k8v*8 + (nt >> 1);
            int l = l0 + (nt & 1)*16 + ll;
            #pragma unroll
            for (int rg = 0; rg < 4; ++rg) {
                int o = m0 - 32 + rg;
                pool[(size_t)(b*32 + o)*MAT + (size_t)v*NN + l]
                    = acc[nt][rg] + 2.f*bp[o];
            }
        }
    } else {
        // embed channels o = m0+reg; pk2 over v pairs: vsub = 2j,2j+1
        // acc index nt = vsub*2 + lh  ->  lo=acc[4j+lh], hi=acc[4j+2+lh]
        #pragma unroll
        for (int lh = 0; lh < 2; ++lh) {
            int l = l0 + lh*16 + ll;
            #pragma unroll
            for (int rg = 0; rg < 4; ++rg) {
                int o = m0 + rg;
                float bias = 2.f * be[o];
                uint4 u;
                u.x = pk2(acc[0  + lh][rg] + bias, acc[2  + lh][rg] + bias);
                u.y = pk2(acc[4  + lh][rg] + bias, acc[6  + lh][rg] + bias);
                u.z = pk2(acc[8  + lh][rg] + bias, acc[10 + lh][rg] + bias);
                u.w = pk2(acc[12 + lh][rg] + bias, acc[14 + lh][rg] + bias);
                *(uint4*)&embed_pk[(size_t)(b*32 + o)*PKSZ
                                   + (size_t)(k8v*160 + l)*4] = u;
            }
        }
    }
}

// ---------------------------------------------------------------------------
// softmax over node dim (read-only input); emits srpk = PK over node-row pairs
// (B-operand of a@s and A-operand of s^T@embed) AND scpk = PK over column
// pairs (A-operand of s@M).  Column-pair values come from the neighbor lane
// via shfl (lane parity == l parity since 160 and 64 are even; pair never
// straddles a wave).  fp32 s is never stored.
// ---------------------------------------------------------------------------
__global__ __launch_bounds__(256) void softmax_n(const float* __restrict__ p,
                                                 u32* __restrict__ srpk,
                                                 u32* __restrict__ scpk)
{
    int idx = blockIdx.x * 256 + threadIdx.x;   // 163,840 columns
    int l  = idx % NN;
    int bo = idx / NN;
    const float* col = p + (size_t)bo * MAT + l;
    float m = -1e30f, s = 0.f;
    for (int n = 0; n < NN; ++n) {
        float v  = col[(size_t)n * NN];
        float mn = fmaxf(m, v);
        s = s * __expf(m - mn) + __expf(v - mn);
        m = mn;
    }
    float inv = 1.f / s;
    u32* sp = srpk + (size_t)bo * PKSZ;
    u32* cp = scpk + (size_t)bo * PKSZ;
    int k8c = l >> 3, jc = (l >> 1) & 3;
    bool wlane = ((l & 1) == 0);
    for (int k2 = 0; k2 < 80; ++k2) {
        float s0 = __expf(col[(size_t)(2*k2)   * NN] - m) * inv;
        float s1 = __expf(col[(size_t)(2*k2+1) * NN] - m) * inv;
        sp[(size_t)((k2 >> 2)*160 + l)*4 + (k2 & 3)] = pk2(s0, s1);
        float t0 = __shfl_down(s0, 1);
        float t1 = __shfl_down(s1, 1);
        if (wlane) {
            cp[(size_t)(k8c*160 + 2*k2)*4 + jc]     = pk2(s0, t0);
            cp[(size_t)(k8c*160 + 2*k2 + 1)*4 + jc] = pk2(s1, t1);
        }
    }
}

// ---------------------------------------------------------------------------
extern "C" void kernel_launch(void* const* d_in, const int* in_sizes, int n_in,
                              void* d_out, int out_size, void* d_ws, size_t ws_size,
                              hipStream_t stream)
{
    const float* x  = (const float*)d_in[0];
    const float* a  = (const float*)d_in[1];
    const float* We = (const float*)d_in[2];
    const float* be = (const float*)d_in[3];
    const float* Wp = (const float*)d_in[4];
    const float* bp = (const float*)d_in[5];

    float* part0 = (float*)d_out;          // pool -> x_new
    float* part1 = part0 + BIG;            // G2 -> a_new

    char* ws = (char*)d_ws;
    // persistent small PK mats
    u32* At12pk = (u32*)(ws + 0);          // 51200 B
    u32* Ah12pk = (u32*)(ws + 51200);
    u32* apk    = (u32*)(ws + 102400);
    u32* Wpk    = (u32*)(ws + 153600);     // 12288 B
    // big regions
    float* B1      = (float*)(ws + 256000);                 // 104,857,600 B: G1 -> srpk+scpk
    u32*   R3      = (u32*)  (ws + 256000 + 104857600);     //  52,428,800 B: x_pk -> embed_pk
    u32*   R4      = (u32*)  (ws + 256000 + 157286400);     //  52,428,800 B: M_pk
    // total: 209,971,200 B
    // prep-phase temps live inside B1 (dead before first bgemm writes B1)
    float* sums = B1;                       // 320 floats
    float* A1f  = (float*)((char*)B1 + 1536);
    float* A2f  = A1f + MAT;
    float* Ab1f = A2f + MAT;
    float* Ab2f = Ab1f + MAT;
    u32* x_pk     = R3;
    u32* embed_pk = R3;
    u32* srpk = (u32*)B1;
    u32* scpk = (u32*)((char*)B1 + 52428800);
    u32* M_pk = R4;

    // ---- prep (tiny) ----
    prep_sums<<<160, 256, 0, stream>>>(a, sums);
    prep_norm<<<100, 256, 0, stream>>>(a, sums, A1f, A2f);
    prep_mm  <<<200, 256, 0, stream>>>(A1f, A2f, Ab1f, Ab2f);
    prep_pk  <<<38, 256, 0, stream>>>(a, A1f, A2f, Ab1f, Ab2f,
                                      At12pk, Ah12pk, apk);
    prep_wpk <<<3, 256, 0, stream>>>(We, Wp, Wpk);
    cvt_x_pk <<<12800, 256, 0, stream>>>(x, x_pk);

    // ---- hop GEMMs (merged: G1 = (At1+At2)@x, G2 = (Ab1+Ab2)@x) ----
    bgemm16<<<BCN, 256, 0, stream>>>(At12pk, 0, x_pk, B1,    0, (u32*)0);  // G1
    bgemm16<<<BCN, 256, 0, stream>>>(Ah12pk, 0, x_pk, part1, 0, (u32*)0);  // G2

    // ---- channel mix (MFMA) + softmax(+packs fused) ----
    chanmix_mm<<<3200, 256, 0, stream>>>(x, B1, part1, Wpk, be, bp,
                                         embed_pk, part0);
    softmax_n<<<640, 256, 0, stream>>>(part0, srpk, scpk);

    // ---- output GEMMs ----
    // M = a@s (PK-only output)
    bgemm16<<<BCN, 256, 0, stream>>>(apk, 0, srpk, (float*)0, 0, M_pk);
    // x_new = s^T @ embed
    bgemm16<<<BCN, 256, 0, stream>>>(srpk, (long)PKSZ, embed_pk, part0, 0, (u32*)0);
    // a_new = s @ M
    bgemm16<<<BCN, 256, 0, stream>>>(scpk, (long)PKSZ, M_pk, part1, 0, (u32*)0);
}